// Round 14
// baseline (39.356 us; speedup 1.0000x reference)
//
#include <hip/hip_runtime.h>
#include <hip/hip_fp16.h>
#include <math.h>

// CLAHE3D: B=C=1, D=H=W=128, GRID=8x8x8 (tiles 16^3, vpt=4096, nt=512), NB=64,
// bandwidth=0.001, clip=4.0 -> limit=256.
//
// 4 dispatches (R12 + k3 b128-row gather):
//   k1: per-tile KDE hist (atomic gate) -> CDF; blk0: M
//   k2: fold d-axis: T1d[d][jk][n] (fp32)
//   k3: 4096 blocks x 128 thr x 4 rows. Lane hoists its n-column of T1d as 32
//       half2 k-pairs; per row: 32 v_pk_fma_f16 fold -> ONE ds_write_b128 into
//       swizzled 16B row (byte 16*(n+(n>>3))); gather = 6 taps x ONE
//       ds_read_b128 (quad slot bijective per 8-row group -> ~8-way on a 1KB
//       transfer, far under the old 24x b32 cost).
//   k4: 512 blocks x 1024 thr: partial reduce + normalize fp16->fp32
//
// ws layout (floats):
//   M    [128][8]      @0      (1024)
//   cdf  [8][64][64]   @1024   (32768)  [i][jk][n], n innermost
//   T1d  [128][64][64] @33792  (524288) [d][jk][n]
//   bmm  [4096][2]     @558080 (8192)
//   oh   [2M halfs]    @566272 (1048576 float-slots) -- only if ws_size allows

#define WS_M    0
#define WS_CDF  1024
#define WS_T1D  (1024 + 32768)
#define WS_BMM  (1024 + 32768 + 524288)
#define WS_OH   (WS_BMM + 8192)
#define WS_NEED_HALF_BYTES ((size_t)(WS_OH + 1048576) * 4)

__device__ __forceinline__ float bspline5(float x) {
    float t = fabsf(x);
    float t2 = t * t, t3 = t2 * t, t4 = t2 * t2, t5 = t4 * t;
    float w0 = 11.0f/20.0f - t2*0.5f + t4*0.25f - t5*(1.0f/12.0f);
    float w1 = 17.0f/40.0f + t*(5.0f/8.0f) - t2*(7.0f/4.0f) + t3*(5.0f/4.0f)
             - t4*(3.0f/8.0f) + t5*(1.0f/24.0f);
    float u = 3.0f - t;
    float w2 = u*u*u*u*u*(1.0f/120.0f);
    return t < 1.0f ? w0 : (t < 2.0f ? w1 : (t < 3.0f ? w2 : 0.0f));
}

// Branch-free quintic tap weights for u = frac(cb) in [0,1).
__device__ __forceinline__ void quintic_w(float u, float wb[6]) {
    float u2 = u*u, u4 = u2*u2, u5 = u4*u;
    float v = 1.0f - u;
    float v2 = v*v, v4 = v2*v2, v5 = v4*v;
    wb[0] = v5 * (1.0f/120.0f);
    wb[5] = u5 * (1.0f/120.0f);
    {
        float t = u + 1.0f;
        float t2 = t*t, t3 = t2*t, t4 = t2*t2, t5 = t4*t;
        wb[1] = 17.0f/40.0f + t*(5.0f/8.0f) - t2*(7.0f/4.0f) + t3*(5.0f/4.0f)
              - t4*(3.0f/8.0f) + t5*(1.0f/24.0f);
    }
    {
        float t = 2.0f - u;
        float t2 = t*t, t3 = t2*t, t4 = t2*t2, t5 = t4*t;
        wb[4] = 17.0f/40.0f + t*(5.0f/8.0f) - t2*(7.0f/4.0f) + t3*(5.0f/4.0f)
              - t4*(3.0f/8.0f) + t5*(1.0f/24.0f);
    }
    wb[2] = 11.0f/20.0f - u2*0.5f + u4*0.25f - u5*(1.0f/12.0f);
    wb[3] = 11.0f/20.0f - v2*0.5f + v4*0.25f - v5*(1.0f/12.0f);
}

// reflect (dct2) boundary for g=8 (period 16), taps in [-3, 10]
__device__ __forceinline__ int reflect16(int t) {
    int r = t & 15;
    return r < 8 ? r : 15 - r;
}

// ---------- k1: per-tile KDE histogram -> clip/redistribute -> CDF ----------
__global__ __launch_bounds__(256) void k1_hist(const float* __restrict__ x,
                                               float* __restrict__ cdfbuf,
                                               float* __restrict__ M) {
    __shared__ float hist[256];                     // 4 waves x 64 bins
    __shared__ float Ml[1024];
    int t = threadIdx.x;
    int b = blockIdx.x;
    hist[t] = 0.0f;
    if (b == 0) {
        #pragma unroll
        for (int i = 0; i < 4; ++i) Ml[i * 256 + t] = 0.0f;
        __syncthreads();
        if (t < 128) {
            const float step = 8.0625f / 127.0f;    // linspace(-0.53125, 7.53125, 128)
            float c = -0.53125f + (float)t * step;
            int base = (int)floorf(c) - 2;
            #pragma unroll
            for (int tt = 0; tt < 6; ++tt) {        // per-thread-exclusive row: no race
                int tap = base + tt;
                Ml[t * 8 + reflect16(tap)] += bspline5(c - (float)tap);
            }
        }
        __syncthreads();
        #pragma unroll
        for (int i = 0; i < 4; ++i) M[i * 256 + t] = Ml[i * 256 + t];
    }
    __syncthreads();

    int ti = b >> 6, tj = (b >> 3) & 7, tk = b & 7;
    int wv = t >> 6;
    const float inv63 = 1.0f / 63.0f;
    int gbase4 = (((ti * 16) * 128 + tj * 16) * 128 + tk * 16) >> 2;
    const float4* x4 = (const float4*)x;
    #pragma unroll
    for (int itv = 0; itv < 4; ++itv) {
        int vi = itv * 256 + t;                     // 1024 float4 per tile
        int c4 = vi & 3, bb = (vi >> 2) & 15, a = vi >> 6;
        float4 v4 = x4[gbase4 + a * 4096 + bb * 32 + c4];
        float vals[4] = {v4.x, v4.y, v4.z, v4.w};
        #pragma unroll
        for (int m = 0; m < 4; ++m) {
            float val = vals[m];
            int b0 = (int)floorf(val * 63.0f + 0.5f);   // nearest bin, in [0,63]
            float q = (val - (float)b0 * inv63) * 1000.0f;
            float q2 = q * q;
            if (q2 <= 36.0f)                        // w >= e^-18; else negligible
                atomicAdd(&hist[wv * 64 + b0], __expf(-0.5f * q2));
        }
    }
    __syncthreads();

    if (t < 64) {                                   // one wave: clip/redistribute/CDF
        float pdf = (hist[t] + hist[64 + t] + hist[128 + t] + hist[192 + t])
                    * (1.0f / 4096.0f);
        float s = pdf;
        #pragma unroll
        for (int off = 32; off >= 1; off >>= 1) s += __shfl_xor(s, off, 64);
        float pdfn = pdf / (s + 1e-10f);
        float histo = fminf(pdfn * 4096.0f, 256.0f);
        float s2 = histo;
        #pragma unroll
        for (int off = 32; off >= 1; off >>= 1) s2 += __shfl_xor(s2, off, 64);
        float clipped = 4096.0f - s2;
        float residual = clipped - floorf(clipped * (1.0f / 64.0f)) * 64.0f;
        float redist = (clipped - residual) * (1.0f / 64.0f);
        float h2 = histo + redist + (((float)t < residual) ? 1.0f : 0.0f);
        float cum = h2;
        #pragma unroll
        for (int off = 1; off < 64; off <<= 1) {
            float p = __shfl_up(cum, off, 64);
            if (t >= off) cum += p;
        }
        cdfbuf[b * 64 + t] = cum * (63.0f / 4096.0f);   // [i][jk][n], coalesced
    }
}

// ---------- k2: fold d: T1d[d][jk][n] = sum_i cdf[i][jk][n] * M[d][i] (float4) ----------
__global__ __launch_bounds__(256) void k2_t1d(const float* __restrict__ cdfbuf,
                                              const float* __restrict__ M,
                                              float* __restrict__ T1d) {
    int i4 = blockIdx.x * 256 + threadIdx.x;        // 131072 float4 ids
    int d = i4 >> 10;                               // 1024 float4 per d
    int o4 = i4 & 1023;
    const float4* c4 = (const float4*)cdfbuf;
    float md[8];
    #pragma unroll
    for (int i = 0; i < 8; ++i) md[i] = M[d * 8 + i];
    float4 s = make_float4(0.f, 0.f, 0.f, 0.f);
    #pragma unroll
    for (int i = 0; i < 8; ++i) {
        float4 c = c4[i * 1024 + o4];
        s.x += c.x * md[i]; s.y += c.y * md[i];
        s.z += c.z * md[i]; s.w += c.w * md[i];
    }
    ((float4*)T1d)[i4] = s;
}

// ---------- k3: 4096 blocks x 128 threads x 4 rows (same d).
//   Fold: lane = (n = lt&63, wave g folds rows 2g,2g+1). Lane hoists its
//   n-column of T1d packed to 32 half2 k-pairs; fold = 32 v_pk_fma_f16/row;
//   8 results packed -> ONE ds_write_b128 to swizzled row byte 16*(n+(n>>3)).
//   Gather: lane = w; per tap ONE ds_read_b128 of the full k-row + 4 hfma2. ----------
template <bool HOUT>
__global__ __launch_bounds__(128) void k3_final(const float* __restrict__ x,
                                                const float* __restrict__ T1d,
                                                const float* __restrict__ M,
                                                float* __restrict__ out,
                                                __half* __restrict__ oh,
                                                float* __restrict__ bmm) {
    __shared__ __align__(16) __half2 t2r[4][288];   // per row: 72 swizzled 16B slots
    __shared__ float smn[2], smx[2];
    const int lt = threadIdx.x;                     // gather: = w
    const int b = blockIdx.x;
    const int d = b >> 5;                           // 32 blocks share each d
    const int n = lt & 63, g = lt >> 6;
    const int row0 = b * 4;                         // d*128 + h0

    // hoist lane's n-column of T1d (stride-64, lane-coalesced), pack k-pairs
    const float* basep = T1d + d * 4096 + n;
    __half2 colH[32];                               // [j][c]: (k=2c, 2c+1)
    #pragma unroll
    for (int jc = 0; jc < 32; ++jc) {
        float f0 = basep[(2 * jc) * 64];
        float f1 = basep[(2 * jc + 1) * 64];
        colH[jc] = __floats2half2_rn(f0, f1);
    }

    // prefetch x values early (latency hides under the folds)
    float vs[4];
    #pragma unroll
    for (int it = 0; it < 4; ++it) vs[it] = x[(row0 + it) * 128 + lt];

    float mw[8];
    #pragma unroll
    for (int k = 0; k < 8; ++k) mw[k] = M[lt * 8 + k];
    __half2 mwh[4];
    #pragma unroll
    for (int c = 0; c < 4; ++c) mwh[c] = __floats2half2_rn(mw[2 * c], mw[2 * c + 1]);

    // ---- fold: wave g handles rows 2g, 2g+1; one b128 write per row ----
    #pragma unroll
    for (int rr = 0; rr < 2; ++rr) {
        int r = 2 * g + rr;
        int h = (row0 + r) & 127;
        __half2 acc[4];
        #pragma unroll
        for (int c = 0; c < 4; ++c) acc[c] = __floats2half2_rn(0.f, 0.f);
        #pragma unroll
        for (int j = 0; j < 8; ++j) {
            __half2 mj2 = __half2half2(__float2half_rn(M[h * 8 + j]));
            #pragma unroll
            for (int c = 0; c < 4; ++c)
                acc[c] = __hfma2(colH[j * 4 + c], mj2, acc[c]);
        }
        float4 wv4;
        ((__half2*)&wv4)[0] = acc[0];
        ((__half2*)&wv4)[1] = acc[1];
        ((__half2*)&wv4)[2] = acc[2];
        ((__half2*)&wv4)[3] = acc[3];
        *(float4*)&t2r[r][4 * (n + (n >> 3))] = wv4;    // ds_write_b128, swizzled
    }
    __syncthreads();                                // the ONLY barrier

    // ---- gather: 4 voxels, 6 taps x ONE ds_read_b128 each ----
    float mn = 3.4e38f, mx = -3.4e38f;
    #pragma unroll
    for (int it = 0; it < 4; ++it) {
        float v = vs[it];
        float cb = v * 63.0f;
        float fl = floorf(cb);
        int basei = (int)fl - 2;
        float wb[6];
        quintic_w(cb - fl, wb);
        float acc = 0.0f;
        #pragma unroll
        for (int tt = 0; tt < 6; ++tt) {
            int tap = basei + tt;                   // in [-2, 66]
            int r2 = tap & 127;                     // reflect period 128
            int nt = r2 < 64 ? r2 : 127 - r2;
            float4 rv = *(const float4*)&t2r[it][4 * (nt + (nt >> 3))];
            __half2 h0 = ((__half2*)&rv)[0];
            __half2 h1 = ((__half2*)&rv)[1];
            __half2 h2 = ((__half2*)&rv)[2];
            __half2 h3 = ((__half2*)&rv)[3];
            __half2 s2 = __hmul2(h0, mwh[0]);
            s2 = __hfma2(h1, mwh[1], s2);
            s2 = __hfma2(h2, mwh[2], s2);
            s2 = __hfma2(h3, mwh[3], s2);
            float s = __low2float(s2) + __high2float(s2);
            acc += wb[tt] * s;
        }
        if (HOUT) {
            __half ha = __float2half_rn(acc);
            float va = __half2float(ha);            // minmax consistent with stored
            oh[(row0 + it) * 128 + lt] = ha;
            mn = fminf(mn, va);
            mx = fmaxf(mx, va);
        } else {
            out[(row0 + it) * 128 + lt] = acc;
            mn = fminf(mn, acc);
            mx = fmaxf(mx, acc);
        }
    }

    // block minmax partial -> bmm[b]
    #pragma unroll
    for (int off = 32; off >= 1; off >>= 1) {
        mn = fminf(mn, __shfl_xor(mn, off, 64));
        mx = fmaxf(mx, __shfl_xor(mx, off, 64));
    }
    int lane = lt & 63, wv = lt >> 6;
    if (lane == 0) { smn[wv] = mn; smx[wv] = mx; }
    __syncthreads();
    if (lt == 0) {
        ((float2*)bmm)[b] = make_float2(fminf(smn[0], smn[1]),
                                        fmaxf(smx[0], smx[1]));
    }
}

// ---------- k4: 512 blocks x 1024 thr: partial reduce + normalize ----------
template <bool HIN>
__global__ __launch_bounds__(1024) void k4_norm(float* __restrict__ out,
                                                const __half* __restrict__ oh,
                                                const float* __restrict__ bmm) {
    __shared__ float smn[16], smx[16], bc[2];
    int t = threadIdx.x;
    // reduce 4096 float2 = 2048 float4 (32 KB, L2-resident), 2 per thread
    const float4* bm4 = (const float4*)bmm;
    float mn = 3.4e38f, mx = -3.4e38f;
    #pragma unroll
    for (int i = 0; i < 2; ++i) {
        float4 r = bm4[i * 1024 + t];
        mn = fminf(mn, fminf(r.x, r.z));
        mx = fmaxf(mx, fmaxf(r.y, r.w));
    }
    #pragma unroll
    for (int off = 32; off >= 1; off >>= 1) {
        mn = fminf(mn, __shfl_xor(mn, off, 64));
        mx = fmaxf(mx, __shfl_xor(mx, off, 64));
    }
    int lane = t & 63, wv = t >> 6;
    if (lane == 0) { smn[wv] = mn; smx[wv] = mx; }
    __syncthreads();
    if (t == 0) {
        float a = smn[0], b = smx[0];
        #pragma unroll
        for (int i = 1; i < 16; ++i) {
            a = fminf(a, smn[i]);
            b = fmaxf(b, smx[i]);
        }
        bc[0] = a; bc[1] = b;
    }
    __syncthreads();
    float m0 = bc[0];
    float sc = 1.0f / (bc[1] - m0 + 1e-10f);
    int idx = blockIdx.x * 1024 + t;                // 524288 float4 ids, 1 per thread
    float4 val;
    if (HIN) {
        const __half2* oh2 = (const __half2*)oh;
        __half2 a = oh2[2 * idx], b2 = oh2[2 * idx + 1];
        val = make_float4(__low2float(a), __high2float(a),
                          __low2float(b2), __high2float(b2));
    } else {
        val = ((const float4*)out)[idx];
    }
    val.x = (val.x - m0) * sc;
    val.y = (val.y - m0) * sc;
    val.z = (val.z - m0) * sc;
    val.w = (val.w - m0) * sc;
    ((float4*)out)[idx] = val;
}

extern "C" void kernel_launch(void* const* d_in, const int* in_sizes, int n_in,
                              void* d_out, int out_size, void* d_ws, size_t ws_size,
                              hipStream_t stream) {
    const float* x = (const float*)d_in[0];
    float* out = (float*)d_out;
    float* ws = (float*)d_ws;
    float* M      = ws + WS_M;
    float* cdfbuf = ws + WS_CDF;
    float* T1d    = ws + WS_T1D;
    float* bmmp   = ws + WS_BMM;
    __half* oh    = (__half*)(ws + WS_OH);
    const bool use_half = ws_size >= WS_NEED_HALF_BYTES;

    hipLaunchKernelGGL(k1_hist, dim3(512), dim3(256), 0, stream, x, cdfbuf, M);
    hipLaunchKernelGGL(k2_t1d,  dim3(512), dim3(256), 0, stream, cdfbuf, M, T1d);
    if (use_half) {
        hipLaunchKernelGGL((k3_final<true>),  dim3(4096), dim3(128),  0, stream,
                           x, T1d, M, out, oh, bmmp);
        hipLaunchKernelGGL((k4_norm<true>),   dim3(512),  dim3(1024), 0, stream,
                           out, oh, bmmp);
    } else {
        hipLaunchKernelGGL((k3_final<false>), dim3(4096), dim3(128),  0, stream,
                           x, T1d, M, out, oh, bmmp);
        hipLaunchKernelGGL((k4_norm<false>),  dim3(512),  dim3(1024), 0, stream,
                           out, oh, bmmp);
    }
}

// Round 15
// 35.810 us; speedup vs baseline: 1.0990x; 1.0990x over previous
//
#include <hip/hip_runtime.h>
#include <hip/hip_fp16.h>
#include <math.h>

// CLAHE3D: B=C=1, D=H=W=128, GRID=8x8x8 (tiles 16^3, vpt=4096, nt=512), NB=64,
// bandwidth=0.001, clip=4.0 -> limit=256.
//
// 4 dispatches (R12 structure = best known 36.5us; T1d stored fp16 in k3's
// consumption layout):
//   k1: per-tile KDE hist (atomic gate) -> CDF; blk0: M
//   k2: fold d-axis -> T1h[d][j][c][n] half2 (c = k-pair (2c,2c+1)), 1 MB
//   k3: 4096 blocks x 128 thr x 4 rows; hoist = 8 coalesced b64 loads/lane;
//       fold = 16 hfma2/row; LDS gather = R12's proven b32 half2 form.
//   k4: 512 blocks x 1024 thr: partial reduce + normalize fp16->fp32
//
// ws layout (floats):
//   M    [128][8]      @0      (1024)
//   cdf  [8][64][64]   @1024   (32768)  [i][jk][n], n innermost
//   T1h  [1MB fp16]    @33792  (262144 float-slots used)
//   bmm  [4096][2]     @558080 (8192)
//   oh   [2M halfs]    @566272 (262144... 1048576 float-slots) -- ws-guarded

#define WS_M    0
#define WS_CDF  1024
#define WS_T1D  (1024 + 32768)
#define WS_BMM  (1024 + 32768 + 524288)
#define WS_OH   (WS_BMM + 8192)
#define WS_NEED_HALF_BYTES ((size_t)(WS_OH + 1048576) * 4)

__device__ __forceinline__ float bspline5(float x) {
    float t = fabsf(x);
    float t2 = t * t, t3 = t2 * t, t4 = t2 * t2, t5 = t4 * t;
    float w0 = 11.0f/20.0f - t2*0.5f + t4*0.25f - t5*(1.0f/12.0f);
    float w1 = 17.0f/40.0f + t*(5.0f/8.0f) - t2*(7.0f/4.0f) + t3*(5.0f/4.0f)
             - t4*(3.0f/8.0f) + t5*(1.0f/24.0f);
    float u = 3.0f - t;
    float w2 = u*u*u*u*u*(1.0f/120.0f);
    return t < 1.0f ? w0 : (t < 2.0f ? w1 : (t < 3.0f ? w2 : 0.0f));
}

// Branch-free quintic tap weights for u = frac(cb) in [0,1).
__device__ __forceinline__ void quintic_w(float u, float wb[6]) {
    float u2 = u*u, u4 = u2*u2, u5 = u4*u;
    float v = 1.0f - u;
    float v2 = v*v, v4 = v2*v2, v5 = v4*v;
    wb[0] = v5 * (1.0f/120.0f);
    wb[5] = u5 * (1.0f/120.0f);
    {
        float t = u + 1.0f;
        float t2 = t*t, t3 = t2*t, t4 = t2*t2, t5 = t4*t;
        wb[1] = 17.0f/40.0f + t*(5.0f/8.0f) - t2*(7.0f/4.0f) + t3*(5.0f/4.0f)
              - t4*(3.0f/8.0f) + t5*(1.0f/24.0f);
    }
    {
        float t = 2.0f - u;
        float t2 = t*t, t3 = t2*t, t4 = t2*t2, t5 = t4*t;
        wb[4] = 17.0f/40.0f + t*(5.0f/8.0f) - t2*(7.0f/4.0f) + t3*(5.0f/4.0f)
              - t4*(3.0f/8.0f) + t5*(1.0f/24.0f);
    }
    wb[2] = 11.0f/20.0f - u2*0.5f + u4*0.25f - u5*(1.0f/12.0f);
    wb[3] = 11.0f/20.0f - v2*0.5f + v4*0.25f - v5*(1.0f/12.0f);
}

// reflect (dct2) boundary for g=8 (period 16), taps in [-3, 10]
__device__ __forceinline__ int reflect16(int t) {
    int r = t & 15;
    return r < 8 ? r : 15 - r;
}

// ---------- k1: per-tile KDE histogram -> clip/redistribute -> CDF ----------
__global__ __launch_bounds__(256) void k1_hist(const float* __restrict__ x,
                                               float* __restrict__ cdfbuf,
                                               float* __restrict__ M) {
    __shared__ float hist[256];                     // 4 waves x 64 bins
    __shared__ float Ml[1024];
    int t = threadIdx.x;
    int b = blockIdx.x;
    hist[t] = 0.0f;
    if (b == 0) {
        #pragma unroll
        for (int i = 0; i < 4; ++i) Ml[i * 256 + t] = 0.0f;
        __syncthreads();
        if (t < 128) {
            const float step = 8.0625f / 127.0f;    // linspace(-0.53125, 7.53125, 128)
            float c = -0.53125f + (float)t * step;
            int base = (int)floorf(c) - 2;
            #pragma unroll
            for (int tt = 0; tt < 6; ++tt) {        // per-thread-exclusive row: no race
                int tap = base + tt;
                Ml[t * 8 + reflect16(tap)] += bspline5(c - (float)tap);
            }
        }
        __syncthreads();
        #pragma unroll
        for (int i = 0; i < 4; ++i) M[i * 256 + t] = Ml[i * 256 + t];
    }
    __syncthreads();

    int ti = b >> 6, tj = (b >> 3) & 7, tk = b & 7;
    int wv = t >> 6;
    const float inv63 = 1.0f / 63.0f;
    int gbase4 = (((ti * 16) * 128 + tj * 16) * 128 + tk * 16) >> 2;
    const float4* x4 = (const float4*)x;
    #pragma unroll
    for (int itv = 0; itv < 4; ++itv) {
        int vi = itv * 256 + t;                     // 1024 float4 per tile
        int c4 = vi & 3, bb = (vi >> 2) & 15, a = vi >> 6;
        float4 v4 = x4[gbase4 + a * 4096 + bb * 32 + c4];
        float vals[4] = {v4.x, v4.y, v4.z, v4.w};
        #pragma unroll
        for (int m = 0; m < 4; ++m) {
            float val = vals[m];
            int b0 = (int)floorf(val * 63.0f + 0.5f);   // nearest bin, in [0,63]
            float q = (val - (float)b0 * inv63) * 1000.0f;
            float q2 = q * q;
            if (q2 <= 36.0f)                        // w >= e^-18; else negligible
                atomicAdd(&hist[wv * 64 + b0], __expf(-0.5f * q2));
        }
    }
    __syncthreads();

    if (t < 64) {                                   // one wave: clip/redistribute/CDF
        float pdf = (hist[t] + hist[64 + t] + hist[128 + t] + hist[192 + t])
                    * (1.0f / 4096.0f);
        float s = pdf;
        #pragma unroll
        for (int off = 32; off >= 1; off >>= 1) s += __shfl_xor(s, off, 64);
        float pdfn = pdf / (s + 1e-10f);
        float histo = fminf(pdfn * 4096.0f, 256.0f);
        float s2 = histo;
        #pragma unroll
        for (int off = 32; off >= 1; off >>= 1) s2 += __shfl_xor(s2, off, 64);
        float clipped = 4096.0f - s2;
        float residual = clipped - floorf(clipped * (1.0f / 64.0f)) * 64.0f;
        float redist = (clipped - residual) * (1.0f / 64.0f);
        float h2 = histo + redist + (((float)t < residual) ? 1.0f : 0.0f);
        float cum = h2;
        #pragma unroll
        for (int off = 1; off < 64; off <<= 1) {
            float p = __shfl_up(cum, off, 64);
            if (t >= off) cum += p;
        }
        cdfbuf[b * 64 + t] = cum * (63.0f / 4096.0f);   // [i][jk][n], coalesced
    }
}

// ---------- k2: fold d -> T1h[d][j][c][n] half2, c = k-pair (2c, 2c+1) ----------
// Thread computes 4 consecutive n for one (d,j,c): 16 L2-resident float4 reads,
// 8 column sums, packs 4 half2, one 16B store.
__global__ __launch_bounds__(256) void k2_t1d(const float* __restrict__ cdfbuf,
                                              const float* __restrict__ M,
                                              __half2* __restrict__ T1h) {
    int i4 = blockIdx.x * 256 + threadIdx.x;        // 65536 ids
    int d = i4 >> 9;                                // 512 per d
    int rem = i4 & 511;                             // j*64 + c*16 + n4
    int j = rem >> 6;
    int c = (rem >> 4) & 3;
    int n4 = rem & 15;
    float md[8];
    #pragma unroll
    for (int i = 0; i < 8; ++i) md[i] = M[d * 8 + i];
    const float4* c4 = (const float4*)cdfbuf;
    int rowa = (j * 8 + 2 * c) * 16 + n4;           // float4 index in a 1024-f4 i-slab
    int rowb = rowa + 16;                           // jk+1
    float4 sa = make_float4(0.f, 0.f, 0.f, 0.f);
    float4 sb = make_float4(0.f, 0.f, 0.f, 0.f);
    #pragma unroll
    for (int i = 0; i < 8; ++i) {
        float m = md[i];
        float4 ca = c4[i * 1024 + rowa];
        float4 cb = c4[i * 1024 + rowb];
        sa.x += ca.x * m; sa.y += ca.y * m; sa.z += ca.z * m; sa.w += ca.w * m;
        sb.x += cb.x * m; sb.y += cb.y * m; sb.z += cb.z * m; sb.w += cb.w * m;
    }
    float4 ov;
    ((__half2*)&ov)[0] = __floats2half2_rn(sa.x, sb.x);
    ((__half2*)&ov)[1] = __floats2half2_rn(sa.y, sb.y);
    ((__half2*)&ov)[2] = __floats2half2_rn(sa.z, sb.z);
    ((__half2*)&ov)[3] = __floats2half2_rn(sa.w, sb.w);
    *(float4*)&T1h[(size_t)d * 2048 + j * 256 + c * 64 + 4 * n4] = ov;
}

// ---------- k3: 4096 blocks x 128 threads x 4 rows (R12 structure, fp16 T1h).
//   Lane (p=lt>>5, m=lt&31): hoist = 8 coalesced b64 loads (cH[j] = half2 pair
//   at n=2m,2m+1); fold = 16 hfma2/row -> one b64 LDS write; gather = R12's
//   proven 6 taps x 4 ds_read_b32 half2 + hfma2 (bank n%32 ~2-way free). ----------
template <bool HOUT>
__global__ __launch_bounds__(128) void k3_final(const float* __restrict__ x,
                                                const __half2* __restrict__ T1h,
                                                const float* __restrict__ M,
                                                float* __restrict__ out,
                                                __half* __restrict__ oh,
                                                float* __restrict__ bmm) {
    __shared__ __half2 t2h[4][256];                 // per row: [p][n] = (k=2p, k=2p+1)
    __shared__ float smn[2], smx[2];
    const int lt = threadIdx.x;                     // = w
    const int b = blockIdx.x;
    const int d = b >> 5;                           // 32 blocks share each d

    const int p = lt >> 5, m = lt & 31;             // k-pair, n-pair index

    // hoist: lane's T1h column (k-pair p; n=2m,2m+1) for all j — 8 b64 loads
    const uint2* colp = (const uint2*)(T1h + (size_t)d * 2048 + p * 64 + 2 * m);
    __half2 cH[8][2];
    #pragma unroll
    for (int j = 0; j < 8; ++j) {
        uint2 u = colp[j * 128];                    // stride 256 half2 = 128 uint2
        cH[j][0] = *(__half2*)&u.x;                 // n = 2m
        cH[j][1] = *(__half2*)&u.y;                 // n = 2m+1
    }

    // prefetch x values early (HBM latency hides under the folds)
    const int row0 = b * 4;                         // d*128 + h0
    float vs[4];
    #pragma unroll
    for (int it = 0; it < 4; ++it) vs[it] = x[(row0 + it) * 128 + lt];

    float mw[8];
    #pragma unroll
    for (int k = 0; k < 8; ++k) mw[k] = M[lt * 8 + k];
    __half2 mwh[4];
    #pragma unroll
    for (int pp = 0; pp < 4; ++pp) mwh[pp] = __floats2half2_rn(mw[2 * pp], mw[2 * pp + 1]);

    // ---- fold ALL 4 rows (16 hfma2 each), write 4 LDS buffers ----
    #pragma unroll
    for (int it = 0; it < 4; ++it) {
        int h = (row0 + it) & 127;
        __half2 hn0 = __floats2half2_rn(0.f, 0.f);
        __half2 hn1 = __floats2half2_rn(0.f, 0.f);
        #pragma unroll
        for (int j = 0; j < 8; ++j) {
            __half2 mj2 = __half2half2(__float2half_rn(M[h * 8 + j]));
            hn0 = __hfma2(cH[j][0], mj2, hn0);
            hn1 = __hfma2(cH[j][1], mj2, hn1);
        }
        __half2* dst = &t2h[it][p * 64 + 2 * m];
        dst[0] = hn0;                               // one b64 write, 2 lanes/bank
        dst[1] = hn1;
    }
    __syncthreads();                                // the ONLY barrier

    // ---- 4 independent gathers ----
    float mn = 3.4e38f, mx = -3.4e38f;
    #pragma unroll
    for (int it = 0; it < 4; ++it) {
        float v = vs[it];
        float cb = v * 63.0f;
        float fl = floorf(cb);
        int basei = (int)fl - 2;
        float wb[6];
        quintic_w(cb - fl, wb);
        const __half2* t2l = t2h[it];
        float acc = 0.0f;
        #pragma unroll
        for (int tt = 0; tt < 6; ++tt) {
            int tap = basei + tt;                   // in [-2, 66]
            int r = tap & 127;                      // reflect period 128
            int n = r < 64 ? r : 127 - r;
            __half2 a0 = t2l[n];                    // 4 x ds_read_b32, imm offsets
            __half2 a1 = t2l[n + 64];
            __half2 a2 = t2l[n + 128];
            __half2 a3 = t2l[n + 192];
            __half2 s2 = __hmul2(a0, mwh[0]);
            s2 = __hfma2(a1, mwh[1], s2);
            s2 = __hfma2(a2, mwh[2], s2);
            s2 = __hfma2(a3, mwh[3], s2);
            float s = __low2float(s2) + __high2float(s2);
            acc += wb[tt] * s;
        }
        if (HOUT) {
            __half ha = __float2half_rn(acc);
            float va = __half2float(ha);            // minmax consistent with stored
            oh[(row0 + it) * 128 + lt] = ha;
            mn = fminf(mn, va);
            mx = fmaxf(mx, va);
        } else {
            out[(row0 + it) * 128 + lt] = acc;
            mn = fminf(mn, acc);
            mx = fmaxf(mx, acc);
        }
    }

    // block minmax partial -> bmm[b]
    #pragma unroll
    for (int off = 32; off >= 1; off >>= 1) {
        mn = fminf(mn, __shfl_xor(mn, off, 64));
        mx = fmaxf(mx, __shfl_xor(mx, off, 64));
    }
    int lane = lt & 63, wv = lt >> 6;
    if (lane == 0) { smn[wv] = mn; smx[wv] = mx; }
    __syncthreads();
    if (lt == 0) {
        ((float2*)bmm)[b] = make_float2(fminf(smn[0], smn[1]),
                                        fmaxf(smx[0], smx[1]));
    }
}

// ---------- k4: 512 blocks x 1024 thr: partial reduce + normalize ----------
template <bool HIN>
__global__ __launch_bounds__(1024) void k4_norm(float* __restrict__ out,
                                                const __half* __restrict__ oh,
                                                const float* __restrict__ bmm) {
    __shared__ float smn[16], smx[16], bc[2];
    int t = threadIdx.x;
    // reduce 4096 float2 = 2048 float4 (32 KB, L2-resident), 2 per thread
    const float4* bm4 = (const float4*)bmm;
    float mn = 3.4e38f, mx = -3.4e38f;
    #pragma unroll
    for (int i = 0; i < 2; ++i) {
        float4 r = bm4[i * 1024 + t];
        mn = fminf(mn, fminf(r.x, r.z));
        mx = fmaxf(mx, fmaxf(r.y, r.w));
    }
    #pragma unroll
    for (int off = 32; off >= 1; off >>= 1) {
        mn = fminf(mn, __shfl_xor(mn, off, 64));
        mx = fmaxf(mx, __shfl_xor(mx, off, 64));
    }
    int lane = t & 63, wv = t >> 6;
    if (lane == 0) { smn[wv] = mn; smx[wv] = mx; }
    __syncthreads();
    if (t == 0) {
        float a = smn[0], b = smx[0];
        #pragma unroll
        for (int i = 1; i < 16; ++i) {
            a = fminf(a, smn[i]);
            b = fmaxf(b, smx[i]);
        }
        bc[0] = a; bc[1] = b;
    }
    __syncthreads();
    float m0 = bc[0];
    float sc = 1.0f / (bc[1] - m0 + 1e-10f);
    int idx = blockIdx.x * 1024 + t;                // 524288 float4 ids, 1 per thread
    float4 val;
    if (HIN) {
        const __half2* oh2 = (const __half2*)oh;
        __half2 a = oh2[2 * idx], b2 = oh2[2 * idx + 1];
        val = make_float4(__low2float(a), __high2float(a),
                          __low2float(b2), __high2float(b2));
    } else {
        val = ((const float4*)out)[idx];
    }
    val.x = (val.x - m0) * sc;
    val.y = (val.y - m0) * sc;
    val.z = (val.z - m0) * sc;
    val.w = (val.w - m0) * sc;
    ((float4*)out)[idx] = val;
}

extern "C" void kernel_launch(void* const* d_in, const int* in_sizes, int n_in,
                              void* d_out, int out_size, void* d_ws, size_t ws_size,
                              hipStream_t stream) {
    const float* x = (const float*)d_in[0];
    float* out = (float*)d_out;
    float* ws = (float*)d_ws;
    float* M       = ws + WS_M;
    float* cdfbuf  = ws + WS_CDF;
    __half2* T1h   = (__half2*)(ws + WS_T1D);
    float* bmmp    = ws + WS_BMM;
    __half* oh     = (__half*)(ws + WS_OH);
    const bool use_half = ws_size >= WS_NEED_HALF_BYTES;

    hipLaunchKernelGGL(k1_hist, dim3(512), dim3(256), 0, stream, x, cdfbuf, M);
    hipLaunchKernelGGL(k2_t1d,  dim3(256), dim3(256), 0, stream, cdfbuf, M, T1h);
    if (use_half) {
        hipLaunchKernelGGL((k3_final<true>),  dim3(4096), dim3(128),  0, stream,
                           x, T1h, M, out, oh, bmmp);
        hipLaunchKernelGGL((k4_norm<true>),   dim3(512),  dim3(1024), 0, stream,
                           out, oh, bmmp);
    } else {
        hipLaunchKernelGGL((k3_final<false>), dim3(4096), dim3(128),  0, stream,
                           x, T1h, M, out, oh, bmmp);
        hipLaunchKernelGGL((k4_norm<false>),  dim3(512),  dim3(1024), 0, stream,
                           out, oh, bmmp);
    }
}